// Round 7
// baseline (404.983 us; speedup 1.0000x reference)
//
#include <hip/hip_runtime.h>
#include <math.h>

// ---------------- constants ----------------
#define BATCH 512
#define DIM 512
#define NCLS 100000
#define NB_TILES 782  // N-tile = 128
#define NPART 1564    // NB_TILES * 2 (wn halves of 64 cols)
#define NB_TILES_FB 782
#define S_SCALE 64.0f
#define COS_M 0.8775825618903728f
#define SIN_M 0.479425538604203f
#define TH_C (-0.8775825618903728f)
#define MM_C 0.2397127693021015f
#define CLIP_LO (-1.0f + 1e-7f)
#define CLIP_HI (1.0f - 1e-7f)

typedef __attribute__((ext_vector_type(8))) short bf16x8;
typedef __attribute__((ext_vector_type(4))) float f32x4;

__device__ __forceinline__ unsigned int f2bf(float x) {
    union { float f; unsigned int u; } v;
    v.f = x;
    return (v.u + 0x7fffu + ((v.u >> 16) & 1u)) >> 16;
}
__device__ __forceinline__ unsigned int pack2(float lo, float hi) {
    return f2bf(lo) | (f2bf(hi) << 16);
}

__device__ __forceinline__ void gld_lds16(const void* g, void* l) {
    __builtin_amdgcn_global_load_lds(
        (const __attribute__((address_space(1))) void*)g,
        (__attribute__((address_space(3))) void*)l, 16, 0, 0);
}

// ---------------- kernel 1: normalize embeddings -> bf16, zero fb sumexp ----
__global__ void k_norm_e(const float* __restrict__ e, short* __restrict__ ebf,
                         float* __restrict__ sumexpz) {
    int row = blockIdx.x;  // 512 rows
    int tid = threadIdx.x; // 128 threads, 4 floats each
    const float4* p = (const float4*)(e + (size_t)row * DIM);
    float4 v = p[tid];
    float ss = v.x * v.x + v.y * v.y + v.z * v.z + v.w * v.w;
    for (int m = 1; m < 64; m <<= 1) ss += __shfl_xor(ss, m, 64);
    __shared__ float wss[2];
    if ((tid & 63) == 0) wss[tid >> 6] = ss;
    __syncthreads();
    float inv = 1.0f / fmaxf(sqrtf(wss[0] + wss[1]), 1e-12f);
    ushort4 o;
    o.x = (unsigned short)f2bf(v.x * inv);
    o.y = (unsigned short)f2bf(v.y * inv);
    o.z = (unsigned short)f2bf(v.z * inv);
    o.w = (unsigned short)f2bf(v.w * inv);
    ((ushort4*)(ebf + (size_t)row * DIM))[tid] = o;
    if (tid == 0) sumexpz[row] = 0.0f;
}

// ---------------- kernel 1b: W fp32 -> bf16 + inv-norms (ONE pass) ---------
__global__ void k_wconv(const float* __restrict__ w, short* __restrict__ wbf,
                        float* __restrict__ wnorm) {
    int tid = threadIdx.x;          // 256 = 4 waves
    int wv = tid >> 6, lane = tid & 63;
    int row = blockIdx.x * 4 + wv;  // grid 25000 -> rows 0..99999
    const float4* src = (const float4*)(w + (size_t)row * DIM);
    float4 a = src[lane];
    float4 b = src[64 + lane];
    float ssq = a.x * a.x + a.y * a.y + a.z * a.z + a.w * a.w +
                b.x * b.x + b.y * b.y + b.z * b.z + b.w * b.w;
#pragma unroll
    for (int m = 1; m < 64; m <<= 1) ssq += __shfl_xor(ssq, m, 64);
    ushort4 oa, ob;
    oa.x = (unsigned short)f2bf(a.x);
    oa.y = (unsigned short)f2bf(a.y);
    oa.z = (unsigned short)f2bf(a.z);
    oa.w = (unsigned short)f2bf(a.w);
    ob.x = (unsigned short)f2bf(b.x);
    ob.y = (unsigned short)f2bf(b.y);
    ob.z = (unsigned short)f2bf(b.z);
    ob.w = (unsigned short)f2bf(b.w);
    ushort4* dst = (ushort4*)(wbf + (size_t)row * DIM);
    dst[lane] = oa;
    dst[64 + lane] = ob;
    if (lane == 0) wnorm[row] = 1.0f / fmaxf(sqrtf(ssq), 1e-12f);
}

// ---------------- kernel 2: pure-DMA GEMM + margin + partial sums ----------
// 256x128 block tile (M=256, N=128), BK=32, 512 threads = 8 waves as
// 4M x 2N; wave tile 64x64 — R4's proven per-wave structure unchanged
// (16 MFMA/kc, same swizzle, same frag reads, 2 blocks/CU, 16 waves/CU).
// vs R4's 128x256: W bf16 L3/L2 re-read halves (4x -> 2x mb passes,
// 410 -> 205 MB); only the L2-resident 512 KB A tile is re-read more.
// Staging: 3 gld_lds16/wave/kc (2 A + 1 B), 3-buffer rotation, counted
// vmcnt(3), one barrier per kc, pre-swizzled global source.
// Epilogue: plain partial stores (no atomics), NPART=1564.
__global__ __launch_bounds__(512, 2) void k_gemm2(
    const short* __restrict__ ebf, const short* __restrict__ wbf,
    const float* __restrict__ wnorm, const int* __restrict__ labels,
    float* __restrict__ partial, float* __restrict__ phiS) {
    __shared__ __align__(16) short As[3][8192];  // 3 x 16KB (256 rows x 32)
    __shared__ __align__(16) short Bs[3][4096];  // 3 x 8KB  (128 rows x 32)
    __shared__ int sLbl[256];

    int bx = blockIdx.x;
    int nb = (bx >> 4) * 8 + (bx & 7);  // mb-siblings share bx&7 (same XCD)
    if (nb >= NB_TILES) return;
    int mb = (bx >> 3) & 1;
    int n0 = nb * 128;

    int tid = threadIdx.x;
    int lane = tid & 63;
    int wv = tid >> 6;            // 0..7
    int wm = wv >> 1, wn = wv & 1;
    int quad = lane >> 4, l16 = lane & 15;

    if (tid < 256) sLbl[tid] = labels[mb * 256 + tid];

    // --- staging addresses (per-lane global, pre-swizzled granule) ---
    // key reduces to lane-only ((l>>2)^(l>>4))&3 for any 16-aligned row base
    int g = (lane & 3) ^ (((lane >> 2) ^ (lane >> 4)) & 3);
    int rr = lane >> 2;  // 0..15 row-within-call
    // A: 2 calls/wave, rows mb*256 + wv*32 + c*16 + rr
    const char* gA0 =
        (const char*)ebf + (size_t)(mb * 256 + wv * 32 + rr) * 1024 + g * 16;
    const char* gA1 = gA0 + 16 * 1024;
    // B: 1 call/wave, rows n0 + wv*16 + rr (clamped)
    int wr = n0 + wv * 16 + rr;
    if (wr > NCLS - 1) wr = NCLS - 1;
    const char* gB = (const char*)wbf + (size_t)wr * 1024 + g * 16;
    int ldsA = wv * 2048;  // wave-uniform A byte base (2 calls x 1024)
    int ldsB = wv * 1024;  // wave-uniform B byte base (1 call x 1024)

#define STAGE(BUF, KC)                                          \
    do {                                                        \
        int kb_ = (KC) * 64;                                    \
        gld_lds16(gA0 + kb_, (char*)&As[BUF][0] + ldsA);        \
        gld_lds16(gA1 + kb_, (char*)&As[BUF][0] + ldsA + 1024); \
        gld_lds16(gB + kb_, (char*)&Bs[BUF][0] + ldsB);         \
    } while (0)

    // --- prologue: stage kc=0,1; drain kc=0 only (kc=1 stays in flight) ---
    STAGE(0, 0);
    STAGE(1, 1);

    f32x4 acc[4][4];
#pragma unroll
    for (int i = 0; i < 4; ++i)
#pragma unroll
        for (int j = 0; j < 4; ++j) acc[i][j] = (f32x4){0.f, 0.f, 0.f, 0.f};

    // --- fragment read bases (same swizzle family as R2-R6) ---
    int go = (quad ^ ((l16 ^ (l16 >> 2)) & 3)) * 8;
    int arowb = (wm * 64 + l16) * 32 + go;
    int browb = (wn * 64 + l16) * 32 + go;

    asm volatile("s_waitcnt vmcnt(3)\n\ts_barrier" ::: "memory");

#pragma unroll
    for (int kc = 0; kc < 16; ++kc) {
        int cur = kc % 3;
        if (kc + 2 < 16) STAGE((kc + 2) % 3, kc + 2);
        {
            bf16x8 af[4], bfr[4];
#pragma unroll
            for (int t = 0; t < 4; ++t)
                af[t] = *(const bf16x8*)&As[cur][arowb + t * 16 * 32];
#pragma unroll
            for (int t = 0; t < 4; ++t)
                bfr[t] = *(const bf16x8*)&Bs[cur][browb + t * 16 * 32];
#pragma unroll
            for (int tm = 0; tm < 4; ++tm)
#pragma unroll
                for (int tn = 0; tn < 4; ++tn)
                    acc[tm][tn] = __builtin_amdgcn_mfma_f32_16x16x32_bf16(
                        af[tm], bfr[tn], acc[tm][tn], 0, 0, 0);
        }
        if (kc < 15) {
            if (kc + 2 < 16)
                asm volatile("s_waitcnt vmcnt(3)\n\ts_barrier" ::: "memory");
            else
                asm volatile("s_waitcnt vmcnt(0)\n\ts_barrier" ::: "memory");
        }
    }
#undef STAGE

    // ---- w scales from precomputed norms ----
    float wscale[4];
#pragma unroll
    for (int tn = 0; tn < 4; ++tn) {
        int col = n0 + wn * 64 + tn * 16 + l16;
        if (col > NCLS - 1) col = NCLS - 1;
        wscale[tn] = wnorm[col];
    }

    // ---- epilogue: scale, clip, margin on label col, exp, per-row reduce --
    float rowsum[16];
#pragma unroll
    for (int i = 0; i < 16; ++i) rowsum[i] = 0.0f;

#pragma unroll
    for (int tm = 0; tm < 4; ++tm) {
#pragma unroll
        for (int r = 0; r < 4; ++r) {
            int m_local = wm * 64 + tm * 16 + quad * 4 + r;
            int lbl = sLbl[m_local];
            float rs = 0.0f;
#pragma unroll
            for (int tn = 0; tn < 4; ++tn) {
                float c = acc[tm][tn][r] * wscale[tn];
                c = fminf(fmaxf(c, CLIP_LO), CLIP_HI);
                int col = n0 + wn * 64 + tn * 16 + l16;
                float t = c;
                if (col == lbl) {
                    float sn = sqrtf(fmaxf(1.0f - c * c, 0.0f));
                    float ph = c * COS_M - sn * SIN_M;
                    ph = (c > TH_C) ? ph : (c - MM_C);
                    t = ph;
                    phiS[mb * 256 + m_local] = S_SCALE * ph;
                }
                float ex = (col < NCLS) ? __expf(S_SCALE * t - 64.0f) : 0.0f;
                rs += ex;
            }
            rowsum[tm * 4 + r] = rs;
        }
    }
    // plain stores: one float per (wave row); slot written exactly once
    float* pbase = partial + (size_t)(nb * 2 + wn) * 512 + mb * 256;
#pragma unroll
    for (int idx = 0; idx < 16; ++idx) {
        float v = rowsum[idx];
        v += __shfl_xor(v, 1, 64);
        v += __shfl_xor(v, 2, 64);
        v += __shfl_xor(v, 4, 64);
        v += __shfl_xor(v, 8, 64);
        if (l16 == idx) {
            int tm = idx >> 2, r = idx & 3;
            int m_local = wm * 64 + tm * 16 + quad * 4 + r;
            pbase[m_local] = v;
        }
    }
}

// ---------------- kernel 2b: reduce partials stage 1 (wide) ----------------
// 8192 threads: thread (seg, col) sums partial[p*512+col] over its ~98-slice.
__global__ void k_rownll(const float* __restrict__ partial,
                         float* __restrict__ part2) {
    int gid = blockIdx.x * 256 + threadIdx.x;  // grid 32 x 256
    int col = ((blockIdx.x & 1) << 8) | threadIdx.x;  // 0..511
    int seg = gid >> 9;                               // 0..15
    int p0 = seg * 98;
    int p1 = p0 + 98; if (p1 > NPART) p1 = NPART;
    float s = 0.0f;
#pragma unroll 4
    for (int p = p0; p < p1; ++p) s += partial[(size_t)p * 512 + col];
    part2[seg * 512 + col] = s;
}

// ---------------- kernel 3: finish sumexp + nll + mean ----------------
__global__ void k_final_mean(const float* __restrict__ part2,
                             const float* __restrict__ phiS,
                             float* __restrict__ out) {
    int tid = threadIdx.x;  // 512
    float s = 0.0f;
#pragma unroll
    for (int seg = 0; seg < 16; ++seg) s += part2[seg * 512 + tid];
    float nll = 64.0f + logf(s) - phiS[tid];
    for (int m = 1; m < 64; m <<= 1) nll += __shfl_xor(nll, m, 64);
    __shared__ float ws[8];
    if ((tid & 63) == 0) ws[tid >> 6] = nll;
    __syncthreads();
    if (tid == 0) {
        float t = 0.0f;
        for (int j = 0; j < 8; ++j) t += ws[j];
        out[0] = t / (float)BATCH;
    }
}

// ---------------- fallback: round-0 fused kernel (small workspace) ----------
__global__ __launch_bounds__(256, 2) void k_gemm_fb(
    const short* __restrict__ ebf, const float* __restrict__ wgt,
    const int* __restrict__ labels, float* __restrict__ sumexp,
    float* __restrict__ phiS) {
    __shared__ __align__(16) short As[128 * 32];
    __shared__ __align__(16) short Bs[128 * 32];
    __shared__ int sLbl[128];
    __shared__ float sWn[128];

    int bx = blockIdx.x;
    int nb = (bx >> 5) * 8 + (bx & 7);
    if (nb >= NB_TILES_FB) return;
    int mb = (bx >> 3) & 3;
    int n0 = nb * 128;

    int tid = threadIdx.x;
    int lane = tid & 63;
    int wv = tid >> 6;
    int wm = wv >> 1, wn = wv & 1;
    int quad = lane >> 4, l16 = lane & 15;

    if (tid < 128) sLbl[tid] = labels[mb * 128 + tid];

    int ar = tid >> 2;
    const short* gA = ebf + (size_t)(mb * 128 + ar) * DIM + (tid & 3) * 8;
    int akey = ((tid >> 2) ^ (tid >> 4)) & 3;
    int aw0 = ar * 32 + ((tid & 3) ^ akey) * 8;

    int br = tid >> 3;
    int gBo[4];
#pragma unroll
    for (int i = 0; i < 4; ++i) {
        int wr = n0 + 32 * i + br;
        if (wr > NCLS - 1) wr = NCLS - 1;
        gBo[i] = wr * DIM + (tid & 7) * 4;
    }
    int bkey = ((tid >> 3) ^ (tid >> 5)) & 3;
    int bw0 = br * 32 + (((tid & 7) >> 1) ^ bkey) * 8 + (tid & 1) * 4;

    f32x4 acc[4][4];
#pragma unroll
    for (int i = 0; i < 4; ++i)
#pragma unroll
        for (int j = 0; j < 4; ++j) acc[i][j] = (f32x4){0.f, 0.f, 0.f, 0.f};
    float ssq[4] = {0.f, 0.f, 0.f, 0.f};

    int go = (quad ^ ((l16 ^ (l16 >> 2)) & 3)) * 8;
    int arowb = (wm * 64 + l16) * 32 + go;
    int browb = (wn * 64 + l16) * 32 + go;

    int4 ra0 = *(const int4*)(gA);
    int4 ra1 = *(const int4*)(gA + 64 * DIM);
    float4 rb0 = *(const float4*)(wgt + gBo[0]);
    float4 rb1 = *(const float4*)(wgt + gBo[1]);
    float4 rb2 = *(const float4*)(wgt + gBo[2]);
    float4 rb3 = *(const float4*)(wgt + gBo[3]);

#pragma unroll 1
    for (int kc = 0; kc < 16; ++kc) {
        *(int4*)&As[aw0] = ra0;
        *(int4*)&As[64 * 32 + aw0] = ra1;
        {
            uint2 p;
            ssq[0] += rb0.x * rb0.x + rb0.y * rb0.y + rb0.z * rb0.z + rb0.w * rb0.w;
            p.x = pack2(rb0.x, rb0.y); p.y = pack2(rb0.z, rb0.w);
            *(uint2*)&Bs[bw0] = p;
            ssq[1] += rb1.x * rb1.x + rb1.y * rb1.y + rb1.z * rb1.z + rb1.w * rb1.w;
            p.x = pack2(rb1.x, rb1.y); p.y = pack2(rb1.z, rb1.w);
            *(uint2*)&Bs[1024 + bw0] = p;
            ssq[2] += rb2.x * rb2.x + rb2.y * rb2.y + rb2.z * rb2.z + rb2.w * rb2.w;
            p.x = pack2(rb2.x, rb2.y); p.y = pack2(rb2.z, rb2.w);
            *(uint2*)&Bs[2048 + bw0] = p;
            ssq[3] += rb3.x * rb3.x + rb3.y * rb3.y + rb3.z * rb3.z + rb3.w * rb3.w;
            p.x = pack2(rb3.x, rb3.y); p.y = pack2(rb3.z, rb3.w);
            *(uint2*)&Bs[3072 + bw0] = p;
        }
        if (kc < 15) {
            int ko = (kc + 1) * 32;
            ra0 = *(const int4*)(gA + ko);
            ra1 = *(const int4*)(gA + 64 * DIM + ko);
            rb0 = *(const float4*)(wgt + gBo[0] + ko);
            rb1 = *(const float4*)(wgt + gBo[1] + ko);
            rb2 = *(const float4*)(wgt + gBo[2] + ko);
            rb3 = *(const float4*)(wgt + gBo[3] + ko);
        }
        asm volatile("s_waitcnt lgkmcnt(0)\n\ts_barrier" ::: "memory");
        {
            bf16x8 af[4], bfr[4];
#pragma unroll
            for (int t = 0; t < 4; ++t)
                af[t] = *(const bf16x8*)&As[arowb + t * 16 * 32];
#pragma unroll
            for (int t = 0; t < 4; ++t)
                bfr[t] = *(const bf16x8*)&Bs[browb + t * 16 * 32];
#pragma unroll
            for (int tm = 0; tm < 4; ++tm)
#pragma unroll
                for (int tn = 0; tn < 4; ++tn)
                    acc[tm][tn] = __builtin_amdgcn_mfma_f32_16x16x32_bf16(
                        af[tm], bfr[tn], acc[tm][tn], 0, 0, 0);
        }
        asm volatile("s_barrier" ::: "memory");
    }

#pragma unroll
    for (int i = 0; i < 4; ++i) {
        float s = ssq[i];
        s += __shfl_xor(s, 1, 64);
        s += __shfl_xor(s, 2, 64);
        s += __shfl_xor(s, 4, 64);
        if ((lane & 7) == 0)
            sWn[32 * i + br] = 1.0f / fmaxf(sqrtf(s), 1e-12f);
    }
    asm volatile("s_waitcnt lgkmcnt(0)\n\ts_barrier" ::: "memory");

    float wscale[4];
#pragma unroll
    for (int tn = 0; tn < 4; ++tn) wscale[tn] = sWn[wn * 64 + tn * 16 + l16];

    float rowsum[16];
#pragma unroll
    for (int i = 0; i < 16; ++i) rowsum[i] = 0.0f;

#pragma unroll
    for (int tm = 0; tm < 4; ++tm) {
#pragma unroll
        for (int r = 0; r < 4; ++r) {
            int m_local = wm * 64 + tm * 16 + quad * 4 + r;
            int lbl = sLbl[m_local];
            float rs = 0.0f;
#pragma unroll
            for (int tn = 0; tn < 4; ++tn) {
                float c = acc[tm][tn][r] * wscale[tn];
                c = fminf(fmaxf(c, CLIP_LO), CLIP_HI);
                int col = n0 + wn * 64 + tn * 16 + l16;
                float t = c;
                if (col == lbl) {
                    float sn = sqrtf(fmaxf(1.0f - c * c, 0.0f));
                    float ph = c * COS_M - sn * SIN_M;
                    ph = (c > TH_C) ? ph : (c - MM_C);
                    t = ph;
                    phiS[mb * 128 + m_local] = S_SCALE * ph;
                }
                float ex = (col < NCLS) ? __expf(S_SCALE * t - 64.0f) : 0.0f;
                rs += ex;
            }
            rowsum[tm * 4 + r] = rs;
        }
    }
#pragma unroll
    for (int idx = 0; idx < 16; ++idx) {
        float v = rowsum[idx];
        v += __shfl_xor(v, 1, 64);
        v += __shfl_xor(v, 2, 64);
        v += __shfl_xor(v, 4, 64);
        v += __shfl_xor(v, 8, 64);
        if (l16 == idx) {
            int tm = idx >> 2, r = idx & 3;
            int m_local = wm * 64 + tm * 16 + quad * 4 + r;
            atomicAdd(&sumexp[mb * 128 + m_local], v);
        }
    }
}

__global__ void k_final_fb(const float* __restrict__ sumexp,
                           const float* __restrict__ phiS,
                           float* __restrict__ out) {
    int tid = threadIdx.x;  // 512
    float nll = 64.0f + logf(sumexp[tid]) - phiS[tid];
    for (int m = 1; m < 64; m <<= 1) nll += __shfl_xor(nll, m, 64);
    __shared__ float ws[8];
    if ((tid & 63) == 0) ws[tid >> 6] = nll;
    __syncthreads();
    if (tid == 0) {
        float s = 0.0f;
        for (int j = 0; j < 8; ++j) s += ws[j];
        out[0] = s / (float)BATCH;
    }
}

// ---------------- launch ----------------
extern "C" void kernel_launch(void* const* d_in, const int* in_sizes, int n_in,
                              void* d_out, int out_size, void* d_ws,
                              size_t ws_size, hipStream_t stream) {
    const float* emb = (const float*)d_in[0];
    const float* wgt = (const float*)d_in[1];
    const int* lbl = (const int*)d_in[2];

    char* ws = (char*)d_ws;
    short* ebf = (short*)ws;                   // 524,288 B
    float* phiS = (float*)(ws + 524288);       // 2,048 B
    float* sumexp_fb = (float*)(ws + 526336);  // 2,048 B
    float* part2 = (float*)(ws + 528384);      // 32,768 B -> ends 561,152
    float* wnorm = (float*)(ws + 561152);      // 400,000 B -> ends 961,152
    float* partial = (float*)(ws + 1048576);   // 3,203,072 B -> ends 4,251,648
    short* wbf = (short*)(ws + 4251648);       // 102,400,000 B

    const size_t NEED = 4251648ull + 102400000ull;

    if (ws_size >= NEED) {
        k_wconv<<<dim3(NCLS / 4), dim3(256), 0, stream>>>(wgt, wbf, wnorm);
        k_norm_e<<<dim3(BATCH), dim3(128), 0, stream>>>(emb, ebf, sumexp_fb);
        k_gemm2<<<dim3(1568), dim3(512), 0, stream>>>(ebf, wbf, wnorm, lbl,
                                                      partial, phiS);
        k_rownll<<<dim3(32), dim3(256), 0, stream>>>(partial, part2);
        k_final_mean<<<dim3(1), dim3(512), 0, stream>>>(part2, phiS,
                                                        (float*)d_out);
    } else {
        k_norm_e<<<dim3(BATCH), dim3(128), 0, stream>>>(emb, ebf, sumexp_fb);
        k_gemm_fb<<<dim3(3136), dim3(256), 0, stream>>>(ebf, wgt, lbl,
                                                        sumexp_fb, phiS);
        k_final_fb<<<dim3(1), dim3(512), 0, stream>>>(sumexp_fb, phiS,
                                                      (float*)d_out);
    }
}

// Round 8
// 375.844 us; speedup vs baseline: 1.0775x; 1.0775x over previous
//
#include <hip/hip_runtime.h>
#include <math.h>

// ---------------- constants ----------------
#define BATCH 512
#define DIM 512
#define NCLS 100000
#define NB_TILES 391  // ceil(NCLS/256) for the 256-wide N tile
#define NPART 1564    // NB_TILES * 4 (wn quarters), ascending 64-col groups
#define NB_TILES_FB 782
#define S_SCALE 64.0f
#define COS_M 0.8775825618903728f
#define SIN_M 0.479425538604203f
#define TH_C (-0.8775825618903728f)
#define MM_C 0.2397127693021015f
#define CLIP_LO (-1.0f + 1e-7f)
#define CLIP_HI (1.0f - 1e-7f)

typedef __attribute__((ext_vector_type(8))) short bf16x8;
typedef __attribute__((ext_vector_type(4))) float f32x4;

__device__ __forceinline__ unsigned int f2bf(float x) {
    union { float f; unsigned int u; } v;
    v.f = x;
    return (v.u + 0x7fffu + ((v.u >> 16) & 1u)) >> 16;
}
__device__ __forceinline__ unsigned int pack2(float lo, float hi) {
    return f2bf(lo) | (f2bf(hi) << 16);
}

__device__ __forceinline__ void gld_lds16(const void* g, void* l) {
    __builtin_amdgcn_global_load_lds(
        (const __attribute__((address_space(1))) void*)g,
        (__attribute__((address_space(3))) void*)l, 16, 0, 0);
}

// ---------------- kernel 1 (merged): W conv + norms, and e-normalize -------
// Blocks [0, 25000): wconv — wave-per-row W fp32 -> bf16 + inv-norm.
// Blocks [25000, 25256): norm_e — 2 embedding rows per block (128 thr each).
// Merging removes one kernel launch + lets the tiny norm_e blocks pack into
// wconv's tail. Numerics of both paths identical to the R4 kernels.
__global__ void k_prep(const float* __restrict__ w, short* __restrict__ wbf,
                       float* __restrict__ wnorm, const float* __restrict__ e,
                       short* __restrict__ ebf, float* __restrict__ sumexpz) {
    int bx = blockIdx.x;
    int tid = threadIdx.x;  // 256
    if (bx < 25000) {
        // ---- wconv body (R4-exact) ----
        int wv = tid >> 6, lane = tid & 63;
        int row = bx * 4 + wv;  // rows 0..99999
        const float4* src = (const float4*)(w + (size_t)row * DIM);
        float4 a = src[lane];
        float4 b = src[64 + lane];
        float ssq = a.x * a.x + a.y * a.y + a.z * a.z + a.w * a.w +
                    b.x * b.x + b.y * b.y + b.z * b.z + b.w * b.w;
#pragma unroll
        for (int m = 1; m < 64; m <<= 1) ssq += __shfl_xor(ssq, m, 64);
        ushort4 oa, ob;
        oa.x = (unsigned short)f2bf(a.x);
        oa.y = (unsigned short)f2bf(a.y);
        oa.z = (unsigned short)f2bf(a.z);
        oa.w = (unsigned short)f2bf(a.w);
        ob.x = (unsigned short)f2bf(b.x);
        ob.y = (unsigned short)f2bf(b.y);
        ob.z = (unsigned short)f2bf(b.z);
        ob.w = (unsigned short)f2bf(b.w);
        ushort4* dst = (ushort4*)(wbf + (size_t)row * DIM);
        dst[lane] = oa;
        dst[64 + lane] = ob;
        if (lane == 0) wnorm[row] = 1.0f / fmaxf(sqrtf(ssq), 1e-12f);
    } else {
        // ---- norm_e body: 2 rows/block, 128 threads each ----
        int grp = tid >> 7;          // 0..1
        int t = tid & 127;           // thread within row-group
        int row = (bx - 25000) * 2 + grp;  // 0..511
        const float4* p = (const float4*)(e + (size_t)row * DIM);
        float4 v = p[t];
        float ss = v.x * v.x + v.y * v.y + v.z * v.z + v.w * v.w;
        for (int m = 1; m < 64; m <<= 1) ss += __shfl_xor(ss, m, 64);
        __shared__ float wss[4];
        if ((tid & 63) == 0) wss[tid >> 6] = ss;
        __syncthreads();
        float inv = 1.0f / fmaxf(sqrtf(wss[2 * grp] + wss[2 * grp + 1]), 1e-12f);
        ushort4 o;
        o.x = (unsigned short)f2bf(v.x * inv);
        o.y = (unsigned short)f2bf(v.y * inv);
        o.z = (unsigned short)f2bf(v.z * inv);
        o.w = (unsigned short)f2bf(v.w * inv);
        ((ushort4*)(ebf + (size_t)row * DIM))[t] = o;
        if (t == 0) sumexpz[row] = 0.0f;
    }
}

// ---------------- kernel 1 (fallback path): normalize embeddings -----------
__global__ void k_norm_e(const float* __restrict__ e, short* __restrict__ ebf,
                         float* __restrict__ sumexpz) {
    int row = blockIdx.x;  // 512 rows
    int tid = threadIdx.x; // 128 threads, 4 floats each
    const float4* p = (const float4*)(e + (size_t)row * DIM);
    float4 v = p[tid];
    float ss = v.x * v.x + v.y * v.y + v.z * v.z + v.w * v.w;
    for (int m = 1; m < 64; m <<= 1) ss += __shfl_xor(ss, m, 64);
    __shared__ float wss[2];
    if ((tid & 63) == 0) wss[tid >> 6] = ss;
    __syncthreads();
    float inv = 1.0f / fmaxf(sqrtf(wss[0] + wss[1]), 1e-12f);
    ushort4 o;
    o.x = (unsigned short)f2bf(v.x * inv);
    o.y = (unsigned short)f2bf(v.y * inv);
    o.z = (unsigned short)f2bf(v.z * inv);
    o.w = (unsigned short)f2bf(v.w * inv);
    ((ushort4*)(ebf + (size_t)row * DIM))[tid] = o;
    if (tid == 0) sumexpz[row] = 0.0f;
}

// ---------------- kernel 2: pure-DMA GEMM + margin + partial sums ----------
// R4-EXACT (the 378.4us configuration). 128x256 tile, 512 threads (8 waves
// as 2M x 4N; wave tile 64x64). BK=32, 3-buffer rotation, counted vmcnt(3)
// (3 gld_lds16 per wave per kc: 1 A + 2 B), one barrier per kc, XOR granule
// swizzle via pre-swizzled per-lane global source. 2 blocks/CU (72.5KB LDS),
// 16 waves/CU. Epilogue: plain partial stores (no atomics).
__global__ __launch_bounds__(512, 4) void k_gemm2(
    const short* __restrict__ ebf, const short* __restrict__ wbf,
    const float* __restrict__ wnorm, const int* __restrict__ labels,
    float* __restrict__ partial, float* __restrict__ phiS) {
    __shared__ __align__(16) short As[3][4096];  // 3 x 8KB  (128 rows)
    __shared__ __align__(16) short Bs[3][8192];  // 3 x 16KB (256 rows)
    __shared__ int sLbl[128];

    int bx = blockIdx.x;
    int nb = (bx >> 5) * 8 + (bx & 7);  // mb-siblings share bx%8 (same XCD)
    if (nb >= NB_TILES) return;
    int mb = (bx >> 3) & 3;
    int n0 = nb * 256;

    int tid = threadIdx.x;
    int lane = tid & 63;
    int wv = tid >> 6;           // 0..7
    int wm = wv >> 2, wn = wv & 3;
    int quad = lane >> 4, l16 = lane & 15;

    // --- staging addresses (per-lane global, pre-swizzled granule) ---
    int g = (lane & 3) ^ (((lane >> 2) ^ (lane >> 4)) & 3);
    int r0 = wv * 16 + (lane >> 2);  // 0..127
    const char* gA = (const char*)ebf + (size_t)(mb * 128 + r0) * (DIM * 2) + g * 16;
    int wr0 = n0 + r0;       if (wr0 > NCLS - 1) wr0 = NCLS - 1;
    int wr1 = n0 + 128 + r0; if (wr1 > NCLS - 1) wr1 = NCLS - 1;
    const char* gB0 = (const char*)wbf + (size_t)wr0 * (DIM * 2) + g * 16;
    const char* gB1 = (const char*)wbf + (size_t)wr1 * (DIM * 2) + g * 16;
    int ldsw = wv * 1024;  // wave-uniform LDS byte base within a call region

#define STAGE(BUF, KC)                                                    \
    do {                                                                  \
        int kb_ = (KC) * 64;                                              \
        gld_lds16(gA + kb_, (char*)&As[BUF][0] + ldsw);                   \
        gld_lds16(gB0 + kb_, (char*)&Bs[BUF][0] + ldsw);                  \
        gld_lds16(gB1 + kb_, (char*)&Bs[BUF][0] + 8192 + ldsw);          \
    } while (0)

    // --- prologue: stage kc=0,1; drain kc=0 only (kc=1 stays in flight) ---
    STAGE(0, 0);
    STAGE(1, 1);

    if (tid < 128) sLbl[tid] = labels[mb * 128 + tid];

    f32x4 acc[4][4];
#pragma unroll
    for (int i = 0; i < 4; ++i)
#pragma unroll
        for (int j = 0; j < 4; ++j) acc[i][j] = (f32x4){0.f, 0.f, 0.f, 0.f};

    // --- fragment read bases ---
    int go = (quad ^ ((l16 ^ (l16 >> 2)) & 3)) * 8;
    int arowb = (wm * 64 + l16) * 32 + go;
    int browb = (wn * 64 + l16) * 32 + go;

    asm volatile("s_waitcnt vmcnt(3)\n\ts_barrier" ::: "memory");

#pragma unroll
    for (int kc = 0; kc < 16; ++kc) {
        int cur = kc % 3;
        if (kc + 2 < 16) STAGE((kc + 2) % 3, kc + 2);
        {
            bf16x8 af[4], bfr[4];
#pragma unroll
            for (int t = 0; t < 4; ++t)
                af[t] = *(const bf16x8*)&As[cur][arowb + t * 16 * 32];
#pragma unroll
            for (int t = 0; t < 4; ++t)
                bfr[t] = *(const bf16x8*)&Bs[cur][browb + t * 16 * 32];
#pragma unroll
            for (int tm = 0; tm < 4; ++tm)
#pragma unroll
                for (int tn = 0; tn < 4; ++tn)
                    acc[tm][tn] = __builtin_amdgcn_mfma_f32_16x16x32_bf16(
                        af[tm], bfr[tn], acc[tm][tn], 0, 0, 0);
        }
        if (kc < 15) {
            if (kc + 2 < 16)
                asm volatile("s_waitcnt vmcnt(3)\n\ts_barrier" ::: "memory");
            else
                asm volatile("s_waitcnt vmcnt(0)\n\ts_barrier" ::: "memory");
        }
    }
#undef STAGE

    // ---- w scales from precomputed norms ----
    float wscale[4];
#pragma unroll
    for (int tn = 0; tn < 4; ++tn) {
        int col = n0 + wn * 64 + tn * 16 + l16;
        if (col > NCLS - 1) col = NCLS - 1;
        wscale[tn] = wnorm[col];
    }

    // ---- epilogue: scale, clip, margin on label col, exp, per-row reduce --
    float rowsum[16];
#pragma unroll
    for (int i = 0; i < 16; ++i) rowsum[i] = 0.0f;

#pragma unroll
    for (int tm = 0; tm < 4; ++tm) {
#pragma unroll
        for (int r = 0; r < 4; ++r) {
            int m_local = wm * 64 + tm * 16 + quad * 4 + r;
            int lbl = sLbl[m_local];
            float rs = 0.0f;
#pragma unroll
            for (int tn = 0; tn < 4; ++tn) {
                float c = acc[tm][tn][r] * wscale[tn];
                c = fminf(fmaxf(c, CLIP_LO), CLIP_HI);
                int col = n0 + wn * 64 + tn * 16 + l16;
                float t = c;
                if (col == lbl) {
                    float sn = sqrtf(fmaxf(1.0f - c * c, 0.0f));
                    float ph = c * COS_M - sn * SIN_M;
                    ph = (c > TH_C) ? ph : (c - MM_C);
                    t = ph;
                    phiS[mb * 128 + m_local] = S_SCALE * ph;
                }
                float ex = (col < NCLS) ? __expf(S_SCALE * t - 64.0f) : 0.0f;
                rs += ex;
            }
            rowsum[tm * 4 + r] = rs;
        }
    }
    // plain stores: one float per (wave row); slot written exactly once
    float* pbase = partial + (size_t)(nb * 4 + wn) * 512 + mb * 128;
#pragma unroll
    for (int idx = 0; idx < 16; ++idx) {
        float v = rowsum[idx];
        v += __shfl_xor(v, 1, 64);
        v += __shfl_xor(v, 2, 64);
        v += __shfl_xor(v, 4, 64);
        v += __shfl_xor(v, 8, 64);
        if (l16 == idx) {
            int tm = idx >> 2, r = idx & 3;
            int m_local = wm * 64 + tm * 16 + quad * 4 + r;
            pbase[m_local] = v;
        }
    }
}

// ---------------- kernel 2b: reduce partials stage 1 (wide) ----------------
__global__ void k_rownll(const float* __restrict__ partial,
                         float* __restrict__ part2) {
    int gid = blockIdx.x * 256 + threadIdx.x;  // grid 32 x 256
    int col = ((blockIdx.x & 1) << 8) | threadIdx.x;  // 0..511
    int seg = gid >> 9;                               // 0..15
    int p0 = seg * 98;
    int p1 = p0 + 98; if (p1 > NPART) p1 = NPART;
    float s = 0.0f;
#pragma unroll 4
    for (int p = p0; p < p1; ++p) s += partial[(size_t)p * 512 + col];
    part2[seg * 512 + col] = s;
}

// ---------------- kernel 3: finish sumexp + nll + mean ----------------
__global__ void k_final_mean(const float* __restrict__ part2,
                             const float* __restrict__ phiS,
                             float* __restrict__ out) {
    int tid = threadIdx.x;  // 512
    float s = 0.0f;
#pragma unroll
    for (int seg = 0; seg < 16; ++seg) s += part2[seg * 512 + tid];
    float nll = 64.0f + logf(s) - phiS[tid];
    for (int m = 1; m < 64; m <<= 1) nll += __shfl_xor(nll, m, 64);
    __shared__ float ws[8];
    if ((tid & 63) == 0) ws[tid >> 6] = nll;
    __syncthreads();
    if (tid == 0) {
        float t = 0.0f;
        for (int j = 0; j < 8; ++j) t += ws[j];
        out[0] = t / (float)BATCH;
    }
}

// ---------------- fallback: round-0 fused kernel (small workspace) ----------
__global__ __launch_bounds__(256, 2) void k_gemm_fb(
    const short* __restrict__ ebf, const float* __restrict__ wgt,
    const int* __restrict__ labels, float* __restrict__ sumexp,
    float* __restrict__ phiS) {
    __shared__ __align__(16) short As[128 * 32];
    __shared__ __align__(16) short Bs[128 * 32];
    __shared__ int sLbl[128];
    __shared__ float sWn[128];

    int bx = blockIdx.x;
    int nb = (bx >> 5) * 8 + (bx & 7);
    if (nb >= NB_TILES_FB) return;
    int mb = (bx >> 3) & 3;
    int n0 = nb * 128;

    int tid = threadIdx.x;
    int lane = tid & 63;
    int wv = tid >> 6;
    int wm = wv >> 1, wn = wv & 1;
    int quad = lane >> 4, l16 = lane & 15;

    if (tid < 128) sLbl[tid] = labels[mb * 128 + tid];

    int ar = tid >> 2;
    const short* gA = ebf + (size_t)(mb * 128 + ar) * DIM + (tid & 3) * 8;
    int akey = ((tid >> 2) ^ (tid >> 4)) & 3;
    int aw0 = ar * 32 + ((tid & 3) ^ akey) * 8;

    int br = tid >> 3;
    int gBo[4];
#pragma unroll
    for (int i = 0; i < 4; ++i) {
        int wr = n0 + 32 * i + br;
        if (wr > NCLS - 1) wr = NCLS - 1;
        gBo[i] = wr * DIM + (tid & 7) * 4;
    }
    int bkey = ((tid >> 3) ^ (tid >> 5)) & 3;
    int bw0 = br * 32 + (((tid & 7) >> 1) ^ bkey) * 8 + (tid & 1) * 4;

    f32x4 acc[4][4];
#pragma unroll
    for (int i = 0; i < 4; ++i)
#pragma unroll
        for (int j = 0; j < 4; ++j) acc[i][j] = (f32x4){0.f, 0.f, 0.f, 0.f};
    float ssq[4] = {0.f, 0.f, 0.f, 0.f};

    int go = (quad ^ ((l16 ^ (l16 >> 2)) & 3)) * 8;
    int arowb = (wm * 64 + l16) * 32 + go;
    int browb = (wn * 64 + l16) * 32 + go;

    int4 ra0 = *(const int4*)(gA);
    int4 ra1 = *(const int4*)(gA + 64 * DIM);
    float4 rb0 = *(const float4*)(wgt + gBo[0]);
    float4 rb1 = *(const float4*)(wgt + gBo[1]);
    float4 rb2 = *(const float4*)(wgt + gBo[2]);
    float4 rb3 = *(const float4*)(wgt + gBo[3]);

#pragma unroll 1
    for (int kc = 0; kc < 16; ++kc) {
        *(int4*)&As[aw0] = ra0;
        *(int4*)&As[64 * 32 + aw0] = ra1;
        {
            uint2 p;
            ssq[0] += rb0.x * rb0.x + rb0.y * rb0.y + rb0.z * rb0.z + rb0.w * rb0.w;
            p.x = pack2(rb0.x, rb0.y); p.y = pack2(rb0.z, rb0.w);
            *(uint2*)&Bs[bw0] = p;
            ssq[1] += rb1.x * rb1.x + rb1.y * rb1.y + rb1.z * rb1.z + rb1.w * rb1.w;
            p.x = pack2(rb1.x, rb1.y); p.y = pack2(rb1.z, rb1.w);
            *(uint2*)&Bs[1024 + bw0] = p;
            ssq[2] += rb2.x * rb2.x + rb2.y * rb2.y + rb2.z * rb2.z + rb2.w * rb2.w;
            p.x = pack2(rb2.x, rb2.y); p.y = pack2(rb2.z, rb2.w);
            *(uint2*)&Bs[2048 + bw0] = p;
            ssq[3] += rb3.x * rb3.x + rb3.y * rb3.y + rb3.z * rb3.z + rb3.w * rb3.w;
            p.x = pack2(rb3.x, rb3.y); p.y = pack2(rb3.z, rb3.w);
            *(uint2*)&Bs[3072 + bw0] = p;
        }
        if (kc < 15) {
            int ko = (kc + 1) * 32;
            ra0 = *(const int4*)(gA + ko);
            ra1 = *(const int4*)(gA + 64 * DIM + ko);
            rb0 = *(const float4*)(wgt + gBo[0] + ko);
            rb1 = *(const float4*)(wgt + gBo[1] + ko);
            rb2 = *(const float4*)(wgt + gBo[2] + ko);
            rb3 = *(const float4*)(wgt + gBo[3] + ko);
        }
        asm volatile("s_waitcnt lgkmcnt(0)\n\ts_barrier" ::: "memory");
        {
            bf16x8 af[4], bfr[4];
#pragma unroll
            for (int t = 0; t < 4; ++t)
                af[t] = *(const bf16x8*)&As[arowb + t * 16 * 32];
#pragma unroll
            for (int t = 0; t < 4; ++t)
                bfr[t] = *(const bf16x8*)&Bs[browb + t * 16 * 32];
#pragma unroll
            for (int tm = 0; tm < 4; ++tm)
#pragma unroll
                for (int tn = 0; tn < 4; ++tn)
                    acc[tm][tn] = __builtin_amdgcn_mfma_f32_16x16x32_bf16(
                        af[tm], bfr[tn], acc[tm][tn], 0, 0, 0);
        }
        asm volatile("s_barrier" ::: "memory");
    }

#pragma unroll
    for (int i = 0; i < 4; ++i) {
        float s = ssq[i];
        s += __shfl_xor(s, 1, 64);
        s += __shfl_xor(s, 2, 64);
        s += __shfl_xor(s, 4, 64);
        if ((lane & 7) == 0)
            sWn[32 * i + br] = 1.0f / fmaxf(sqrtf(s), 1e-12f);
    }
    asm volatile("s_waitcnt lgkmcnt(0)\n\ts_barrier" ::: "memory");

    float wscale[4];
#pragma unroll
    for (int tn = 0; tn < 4; ++tn) wscale[tn] = sWn[wn * 64 + tn * 16 + l16];

    float rowsum[16];
#pragma unroll
    for (int i = 0; i < 16; ++i) rowsum[i] = 0.0f;

#pragma unroll
    for (int tm = 0; tm < 4; ++tm) {
#pragma unroll
        for (int r = 0; r < 4; ++r) {
            int m_local = wm * 64 + tm * 16 + quad * 4 + r;
            int lbl = sLbl[m_local];
            float rs = 0.0f;
#pragma unroll
            for (int tn = 0; tn < 4; ++tn) {
                float c = acc[tm][tn][r] * wscale[tn];
                c = fminf(fmaxf(c, CLIP_LO), CLIP_HI);
                int col = n0 + wn * 64 + tn * 16 + l16;
                float t = c;
                if (col == lbl) {
                    float sn = sqrtf(fmaxf(1.0f - c * c, 0.0f));
                    float ph = c * COS_M - sn * SIN_M;
                    ph = (c > TH_C) ? ph : (c - MM_C);
                    t = ph;
                    phiS[mb * 128 + m_local] = S_SCALE * ph;
                }
                float ex = (col < NCLS) ? __expf(S_SCALE * t - 64.0f) : 0.0f;
                rs += ex;
            }
            rowsum[tm * 4 + r] = rs;
        }
    }
#pragma unroll
    for (int idx = 0; idx < 16; ++idx) {
        float v = rowsum[idx];
        v += __shfl_xor(v, 1, 64);
        v += __shfl_xor(v, 2, 64);
        v += __shfl_xor(v, 4, 64);
        v += __shfl_xor(v, 8, 64);
        if (l16 == idx) {
            int tm = idx >> 2, r = idx & 3;
            int m_local = wm * 64 + tm * 16 + quad * 4 + r;
            atomicAdd(&sumexp[mb * 128 + m_local], v);
        }
    }
}

__global__ void k_final_fb(const float* __restrict__ sumexp,
                           const float* __restrict__ phiS,
                           float* __restrict__ out) {
    int tid = threadIdx.x;  // 512
    float nll = 64.0f + logf(sumexp[tid]) - phiS[tid];
    for (int m = 1; m < 64; m <<= 1) nll += __shfl_xor(nll, m, 64);
    __shared__ float ws[8];
    if ((tid & 63) == 0) ws[tid >> 6] = nll;
    __syncthreads();
    if (tid == 0) {
        float s = 0.0f;
        for (int j = 0; j < 8; ++j) s += ws[j];
        out[0] = s / (float)BATCH;
    }
}

// ---------------- launch ----------------
extern "C" void kernel_launch(void* const* d_in, const int* in_sizes, int n_in,
                              void* d_out, int out_size, void* d_ws,
                              size_t ws_size, hipStream_t stream) {
    const float* emb = (const float*)d_in[0];
    const float* wgt = (const float*)d_in[1];
    const int* lbl = (const int*)d_in[2];

    char* ws = (char*)d_ws;
    short* ebf = (short*)ws;                   // 524,288 B
    float* phiS = (float*)(ws + 524288);       // 2,048 B
    float* sumexp_fb = (float*)(ws + 526336);  // 2,048 B
    float* part2 = (float*)(ws + 528384);      // 32,768 B -> ends 561,152
    float* wnorm = (float*)(ws + 561152);      // 400,000 B -> ends 961,152
    float* partial = (float*)(ws + 1048576);   // 3,203,072 B -> ends 4,251,648
    short* wbf = (short*)(ws + 4251648);       // 102,400,000 B

    const size_t NEED = 4251648ull + 102400000ull;

    if (ws_size >= NEED) {
        k_prep<<<dim3(25000 + 256), dim3(256), 0, stream>>>(
            wgt, wbf, wnorm, emb, ebf, sumexp_fb);
        k_gemm2<<<dim3(1568), dim3(512), 0, stream>>>(ebf, wbf, wnorm, lbl,
                                                      partial, phiS);
        k_rownll<<<dim3(32), dim3(256), 0, stream>>>(partial, part2);
        k_final_mean<<<dim3(1), dim3(512), 0, stream>>>(part2, phiS,
                                                        (float*)d_out);
    } else {
        k_norm_e<<<dim3(BATCH), dim3(128), 0, stream>>>(emb, ebf, sumexp_fb);
        k_gemm_fb<<<dim3(3136), dim3(256), 0, stream>>>(ebf, wgt, lbl,
                                                        sumexp_fb, phiS);
        k_final_fb<<<dim3(1), dim3(512), 0, stream>>>(sumexp_fb, phiS,
                                                      (float*)d_out);
    }
}